// Round 1
// baseline (485.934 us; speedup 1.0000x reference)
//
#include <hip/hip_runtime.h>
#include <hip/hip_bf16.h>

typedef float f4 __attribute__((ext_vector_type(4)));

// ---------------- degree count: cnt[d] += 1 over real edges ----------------
__global__ __launch_bounds__(256) void deg_k(const int* __restrict__ dst, int* __restrict__ cnt, int E) {
    int e = blockIdx.x * 256 + threadIdx.x;
    if (e < E) atomicAdd(&cnt[dst[e]], 1);
}

// ---------------- dinv[i] = rsqrt(deg_i + 1)  (self loop) ----------------
__global__ __launch_bounds__(256) void dinv_k(const int* __restrict__ cnt, float* __restrict__ dinv, int N) {
    int i = blockIdx.x * 256 + threadIdx.x;
    if (i < N) dinv[i] = rsqrtf((float)(cnt[i] + 1));
}

// ---------------- 3-phase exclusive scan of cnt -> row_ptr (+cursor copy) ----------------
__global__ __launch_bounds__(256) void scan_part(const int* __restrict__ cnt, int* __restrict__ csums, int N) {
    __shared__ int sd[256];
    int b = blockIdx.x, tid = threadIdx.x;
    int base = b * 1024;
    int s = 0;
    for (int i = tid; i < 1024; i += 256) {
        int idx = base + i;
        if (idx < N) s += cnt[idx];
    }
    sd[tid] = s; __syncthreads();
    for (int off = 128; off > 0; off >>= 1) {
        if (tid < off) sd[tid] += sd[tid + off];
        __syncthreads();
    }
    if (tid == 0) csums[b] = sd[0];
}

__global__ __launch_bounds__(256) void scan_top(int* __restrict__ csums, int nchunks) {
    __shared__ int sd[256];
    int tid = threadIdx.x;
    int v = (tid < nchunks) ? csums[tid] : 0;
    int acc = v;
    sd[tid] = v; __syncthreads();
    for (int off = 1; off < 256; off <<= 1) {
        int t = (tid >= off) ? sd[tid - off] : 0;
        __syncthreads();
        acc += t; sd[tid] = acc;
        __syncthreads();
    }
    if (tid < nchunks) csums[tid] = acc - v;   // exclusive
}

__global__ __launch_bounds__(256) void scan_chunk(const int* __restrict__ cnt, const int* __restrict__ csums,
                                                  int* __restrict__ row_ptr, int* __restrict__ cursor, int N) {
    __shared__ int sd[256];
    int b = blockIdx.x, tid = threadIdx.x;
    int base = b * 1024 + tid * 4;
    int v[4];
    #pragma unroll
    for (int j = 0; j < 4; ++j) v[j] = (base + j < N) ? cnt[base + j] : 0;
    int tsum = v[0] + v[1] + v[2] + v[3];
    int acc = tsum;
    sd[tid] = tsum; __syncthreads();
    for (int off = 1; off < 256; off <<= 1) {
        int t = (tid >= off) ? sd[tid - off] : 0;
        __syncthreads();
        acc += t; sd[tid] = acc;
        __syncthreads();
    }
    int excl = acc - tsum + csums[b];
    #pragma unroll
    for (int j = 0; j < 4; ++j) {
        if (base + j < N) { row_ptr[base + j] = excl; cursor[base + j] = excl; excl += v[j]; }
    }
}

// ---------------- CSR fill: col grouped by dst ----------------
__global__ __launch_bounds__(256) void fill_k(const int* __restrict__ src, const int* __restrict__ dst,
                                              int* __restrict__ cursor, int* __restrict__ col, int E) {
    int e = blockIdx.x * 256 + threadIdx.x;
    if (e < E) {
        int d = dst[e];
        int p = atomicAdd(&cursor[d], 1);
        col[p] = src[e];
    }
}

// ---------------- GEMM1: hs = dinv[r] * (x @ W1),  [N,128]@[128,64] ----------------
__global__ __launch_bounds__(256) void gemm1_k(const float* __restrict__ x, const float* __restrict__ W1,
                                               const float* __restrict__ dinv, float* __restrict__ hs, int N) {
    __shared__ float xT[128][64];   // k-major x tile
    __shared__ float wS[128][64];
    const int tid = threadIdx.x;
    const int row0 = blockIdx.x * 64;

    {   // W1: 8192 floats = 2048 f4, contiguous
        const f4* wsrc = (const f4*)W1;
        f4* wdst = (f4*)&wS[0][0];
        #pragma unroll
        for (int i = 0; i < 8; ++i) wdst[tid + i * 256] = wsrc[tid + i * 256];
    }
    {   // x tile rows row0..row0+63, transposed into LDS (conflict-free b32 writes)
        #pragma unroll
        for (int it = 0; it < 8; ++it) {
            int i = tid + it * 256;      // 0..2047
            int r = i & 63;
            int k4 = (i >> 6) * 4;       // 0..124
            int row = row0 + r;
            f4 v = (f4)(0.0f);
            if (row < N) v = *(const f4*)(x + (size_t)row * 128 + k4);
            xT[k4 + 0][r] = v.x; xT[k4 + 1][r] = v.y;
            xT[k4 + 2][r] = v.z; xT[k4 + 3][r] = v.w;
        }
    }
    __syncthreads();

    const int rl = (tid & 15) * 4;    // local rows rl..rl+3
    const int c0 = (tid >> 4) * 4;    // cols c0..c0+3
    f4 acc0 = (f4)(0.0f), acc1 = (f4)(0.0f), acc2 = (f4)(0.0f), acc3 = (f4)(0.0f);
    #pragma unroll 8
    for (int k = 0; k < 128; ++k) {
        f4 xa = *(const f4*)&xT[k][rl];
        f4 wb = *(const f4*)&wS[k][c0];
        acc0 += xa.x * wb;
        acc1 += xa.y * wb;
        acc2 += xa.z * wb;
        acc3 += xa.w * wb;
    }
    #pragma unroll
    for (int i = 0; i < 4; ++i) {
        int row = row0 + rl + i;
        if (row < N) {
            float di = dinv[row];
            f4 a = (i == 0) ? acc0 : (i == 1) ? acc1 : (i == 2) ? acc2 : acc3;
            *(f4*)(hs + (size_t)row * 64 + c0) = a * di;
        }
    }
}

// ---------------- AGG1: h1[i][c] = tanh( dinv[i]*(sum_nb hs[s][c] + hs[i][c]) + b1[c] ), wave per node ----------------
__global__ __launch_bounds__(256) void agg1_k(const float* __restrict__ hs, const int* __restrict__ row_ptr,
                                              const int* __restrict__ cnt, const int* __restrict__ col,
                                              const float* __restrict__ dinv, const float* __restrict__ b1,
                                              float* __restrict__ h1, int N) {
    int wid = blockIdx.x * 4 + (threadIdx.x >> 6);
    int lane = threadIdx.x & 63;
    if (wid >= N) return;
    int beg = row_ptr[wid];
    int num = cnt[wid];
    float acc = 0.0f;
    for (int e0 = 0; e0 < num; e0 += 64) {
        int rem = num - e0;
        int el = 0;
        if (lane < rem) el = col[beg + e0 + lane];
        int m = rem < 64 ? rem : 64;
        int e = 0;
        for (; e + 4 <= m; e += 4) {
            int s0 = __shfl(el, e + 0), s1 = __shfl(el, e + 1);
            int s2 = __shfl(el, e + 2), s3 = __shfl(el, e + 3);
            float v0 = hs[(size_t)s0 * 64 + lane];
            float v1 = hs[(size_t)s1 * 64 + lane];
            float v2 = hs[(size_t)s2 * 64 + lane];
            float v3 = hs[(size_t)s3 * 64 + lane];
            acc += (v0 + v1) + (v2 + v3);
        }
        for (; e < m; ++e) {
            int s = __shfl(el, e);
            acc += hs[(size_t)s * 64 + lane];
        }
    }
    float di = dinv[wid];
    float self = hs[(size_t)wid * 64 + lane];
    h1[(size_t)wid * 64 + lane] = tanhf(di * (acc + self) + b1[lane]);
}

// ---------------- GEMM2: h2s = dinv[r] * (h1 @ W2), [N,64]@[64,16] ----------------
__global__ __launch_bounds__(256) void gemm2_k(const float* __restrict__ h1, const float* __restrict__ W2,
                                               const float* __restrict__ dinv, float* __restrict__ h2s, int N) {
    __shared__ f4 wS[256];   // [k][c4] 64x4
    int tid = threadIdx.x;
    wS[tid] = ((const f4*)W2)[tid];
    __syncthreads();
    int r = blockIdx.x * 256 + tid;
    if (r >= N) return;
    f4 a0 = (f4)(0.0f), a1 = (f4)(0.0f), a2 = (f4)(0.0f), a3 = (f4)(0.0f);
    const float* xr = h1 + (size_t)r * 64;
    #pragma unroll
    for (int k4 = 0; k4 < 16; ++k4) {
        f4 xv = *(const f4*)(xr + k4 * 4);
        #pragma unroll
        for (int kk = 0; kk < 4; ++kk) {
            int k = k4 * 4 + kk;
            float xs = xv[kk];
            a0 += xs * wS[k * 4 + 0];
            a1 += xs * wS[k * 4 + 1];
            a2 += xs * wS[k * 4 + 2];
            a3 += xs * wS[k * 4 + 3];
        }
    }
    float di = dinv[r];
    f4* o = (f4*)(h2s + (size_t)r * 16);
    o[0] = a0 * di; o[1] = a1 * di; o[2] = a2 * di; o[3] = a3 * di;
}

// ---------------- AGG2: 16 channels, quarter-wave per node ----------------
__global__ __launch_bounds__(256) void agg2_k(const float* __restrict__ h2s, const int* __restrict__ row_ptr,
                                              const int* __restrict__ cnt, const int* __restrict__ col,
                                              const float* __restrict__ dinv, const float* __restrict__ b2,
                                              float* __restrict__ h2, int N) {
    int t = blockIdx.x * 256 + threadIdx.x;
    int node = t >> 4;
    int c = t & 15;
    int sub = (threadIdx.x >> 4) & 3;   // quarter within wave
    if (node >= N) return;
    int beg = row_ptr[node];
    int num = cnt[node];
    float acc = 0.0f;
    for (int e0 = 0; e0 < num; e0 += 16) {
        int rem = num - e0;
        int el = 0;
        if (c < rem) el = col[beg + e0 + c];
        int m = rem < 16 ? rem : 16;
        for (int e = 0; e < m; ++e) {
            int s = __shfl(el, (sub << 4) + e);
            acc += h2s[(size_t)s * 16 + c];
        }
    }
    float di = dinv[node];
    float self = h2s[(size_t)node * 16 + c];
    h2[(size_t)node * 16 + c] = tanhf(di * (acc + self) + b2[c]);
}

// ---------------- pool accumulate ----------------
__global__ __launch_bounds__(256) void pool_k(const float* __restrict__ h2, const int* __restrict__ batch,
                                              float* __restrict__ psum, float* __restrict__ pcnt, int N) {
    int t = blockIdx.x * 256 + threadIdx.x;
    if (t >= N * 16) return;
    int node = t >> 4, c = t & 15;
    int g = batch[node];
    atomicAdd(&psum[g * 16 + c], h2[t]);
    if (c == 0) atomicAdd(&pcnt[g], 1.0f);
}

// ---------------- final: sigmoid(mean) ----------------
__global__ __launch_bounds__(256) void final_k(const float* __restrict__ psum, const float* __restrict__ pcnt,
                                               float* __restrict__ out, int M) {
    int t = blockIdx.x * 256 + threadIdx.x;
    if (t < M) {
        int g = t >> 4;
        float cg = fmaxf(pcnt[g], 1.0f);
        float m = psum[t] / cg;
        out[t] = 1.0f / (1.0f + expf(-m));
    }
}

extern "C" void kernel_launch(void* const* d_in, const int* in_sizes, int n_in,
                              void* d_out, int out_size, void* d_ws, size_t ws_size,
                              hipStream_t stream) {
    const float* x     = (const float*)d_in[0];
    const int*   ei    = (const int*)d_in[1];
    const int*   batch = (const int*)d_in[2];
    const float* W1    = (const float*)d_in[3];
    const float* b1    = (const float*)d_in[4];
    const float* W2    = (const float*)d_in[5];
    const float* b2    = (const float*)d_in[6];
    float* out = (float*)d_out;

    const int N = in_sizes[2];
    const int E = in_sizes[1] / 2;
    const int G = out_size / 16;
    const int* src = ei;
    const int* dst = ei + E;

    char* w = (char*)d_ws;
    int*   cnt      = (int*)w;    w += (size_t)N * 4;
    float* psum     = (float*)w;  w += (size_t)G * 64;
    float* pcnt     = (float*)w;  w += (size_t)G * 4;
    int*   row_ptr  = (int*)w;    w += (size_t)N * 4;
    int*   cursor   = (int*)w;    w += (size_t)N * 4;
    float* dinv     = (float*)w;  w += (size_t)N * 4;
    int*   csums    = (int*)w;    w += 1024;
    int*   col      = (int*)w;    w += (size_t)E * 4;
    float* hs       = (float*)w;  w += (size_t)N * 64 * 4;
    float* h1       = (float*)w;  w += (size_t)N * 64 * 4;
    float* h2s      = (float*)w;  w += (size_t)N * 16 * 4;
    float* h2       = (float*)w;  w += (size_t)N * 16 * 4;

    // zero cnt + psum + pcnt (contiguous)
    hipMemsetAsync(cnt, 0, (size_t)N * 4 + (size_t)G * 68, stream);

    int nch = (N + 1023) / 1024;   // 98 for N=100000 (must be <=256)

    deg_k   <<<(E + 255) / 256, 256, 0, stream>>>(dst, cnt, E);
    dinv_k  <<<(N + 255) / 256, 256, 0, stream>>>(cnt, dinv, N);
    scan_part<<<nch, 256, 0, stream>>>(cnt, csums, N);
    scan_top <<<1, 256, 0, stream>>>(csums, nch);
    scan_chunk<<<nch, 256, 0, stream>>>(cnt, csums, row_ptr, cursor, N);
    fill_k  <<<(E + 255) / 256, 256, 0, stream>>>(src, dst, cursor, col, E);

    gemm1_k <<<(N + 63) / 64, 256, 0, stream>>>(x, W1, dinv, hs, N);
    agg1_k  <<<(N + 3) / 4, 256, 0, stream>>>(hs, row_ptr, cnt, col, dinv, b1, h1, N);
    gemm2_k <<<(N + 255) / 256, 256, 0, stream>>>(h1, W2, dinv, h2s, N);
    agg2_k  <<<((size_t)N * 16 + 255) / 256, 256, 0, stream>>>(h2s, row_ptr, cnt, col, dinv, b2, h2, N);
    pool_k  <<<((size_t)N * 16 + 255) / 256, 256, 0, stream>>>(h2, batch, psum, pcnt, N);
    final_k <<<(G * 16 + 255) / 256, 256, 0, stream>>>(psum, pcnt, out, G * 16);
}

// Round 5
// 378.923 us; speedup vs baseline: 1.2824x; 1.2824x over previous
//
#include <hip/hip_runtime.h>
#include <hip/hip_bf16.h>

typedef float f4 __attribute__((ext_vector_type(4)));

// ---------------- degree count: cnt[d] += 1 over real edges ----------------
__global__ __launch_bounds__(256) void deg_k(const int* __restrict__ dst, int* __restrict__ cnt, int E) {
    int e = blockIdx.x * 256 + threadIdx.x;
    if (e < E) atomicAdd(&cnt[dst[e]], 1);
}

// ---------------- dinv[i] = rsqrt(deg_i + 1)  (self loop) ----------------
__global__ __launch_bounds__(256) void dinv_k(const int* __restrict__ cnt, float* __restrict__ dinv, int N) {
    int i = blockIdx.x * 256 + threadIdx.x;
    if (i < N) dinv[i] = rsqrtf((float)(cnt[i] + 1));
}

// ---------------- 3-phase exclusive scan of cnt -> row_ptr (+cursor copy) ----------------
__global__ __launch_bounds__(256) void scan_part(const int* __restrict__ cnt, int* __restrict__ csums, int N) {
    __shared__ int sd[256];
    int b = blockIdx.x, tid = threadIdx.x;
    int base = b * 1024;
    int s = 0;
    for (int i = tid; i < 1024; i += 256) {
        int idx = base + i;
        if (idx < N) s += cnt[idx];
    }
    sd[tid] = s; __syncthreads();
    for (int off = 128; off > 0; off >>= 1) {
        if (tid < off) sd[tid] += sd[tid + off];
        __syncthreads();
    }
    if (tid == 0) csums[b] = sd[0];
}

__global__ __launch_bounds__(256) void scan_top(int* __restrict__ csums, int nchunks) {
    __shared__ int sd[256];
    int tid = threadIdx.x;
    int v = (tid < nchunks) ? csums[tid] : 0;
    int acc = v;
    sd[tid] = v; __syncthreads();
    for (int off = 1; off < 256; off <<= 1) {
        int t = (tid >= off) ? sd[tid - off] : 0;
        __syncthreads();
        acc += t; sd[tid] = acc;
        __syncthreads();
    }
    if (tid < nchunks) csums[tid] = acc - v;   // exclusive
}

__global__ __launch_bounds__(256) void scan_chunk(const int* __restrict__ cnt, const int* __restrict__ csums,
                                                  int* __restrict__ row_ptr, int* __restrict__ cursor, int N) {
    __shared__ int sd[256];
    int b = blockIdx.x, tid = threadIdx.x;
    int base = b * 1024 + tid * 4;
    int v[4];
    #pragma unroll
    for (int j = 0; j < 4; ++j) v[j] = (base + j < N) ? cnt[base + j] : 0;
    int tsum = v[0] + v[1] + v[2] + v[3];
    int acc = tsum;
    sd[tid] = tsum; __syncthreads();
    for (int off = 1; off < 256; off <<= 1) {
        int t = (tid >= off) ? sd[tid - off] : 0;
        __syncthreads();
        acc += t; sd[tid] = acc;
        __syncthreads();
    }
    int excl = acc - tsum + csums[b];
    #pragma unroll
    for (int j = 0; j < 4; ++j) {
        if (base + j < N) { row_ptr[base + j] = excl; cursor[base + j] = excl; excl += v[j]; }
    }
}

// ---------------- CSR fill: col grouped by dst ----------------
__global__ __launch_bounds__(256) void fill_k(const int* __restrict__ src, const int* __restrict__ dst,
                                              int* __restrict__ cursor, int* __restrict__ col, int E) {
    int e = blockIdx.x * 256 + threadIdx.x;
    if (e < E) {
        int d = dst[e];
        int p = atomicAdd(&cursor[d], 1);
        col[p] = src[e];
    }
}

// ---------------- graph boundaries from sorted batch: gstart[g] = first node with batch >= g ----------------
__global__ __launch_bounds__(256) void gbound_k(const int* __restrict__ batch, int* __restrict__ gstart,
                                                int N, int G) {
    int i = blockIdx.x * 256 + threadIdx.x;
    if (i >= N) return;
    int b = batch[i];
    int prev = (i == 0) ? -1 : batch[i - 1];
    for (int g = prev + 1; g <= b; ++g) gstart[g] = i;
    if (i == N - 1) {
        for (int g = b + 1; g <= G; ++g) gstart[g] = N;
    }
}

// ---------------- GEMM1: hs = dinv[r] * (x @ W1),  [N,128]@[128,64] ----------------
__global__ __launch_bounds__(256) void gemm1_k(const float* __restrict__ x, const float* __restrict__ W1,
                                               const float* __restrict__ dinv, float* __restrict__ hs, int N) {
    __shared__ float xT[128][64];   // k-major x tile
    __shared__ float wS[128][64];
    const int tid = threadIdx.x;
    const int row0 = blockIdx.x * 64;

    {   // W1: 8192 floats = 2048 f4, contiguous
        const f4* wsrc = (const f4*)W1;
        f4* wdst = (f4*)&wS[0][0];
        #pragma unroll
        for (int i = 0; i < 8; ++i) wdst[tid + i * 256] = wsrc[tid + i * 256];
    }
    {   // x tile rows row0..row0+63, transposed into LDS (conflict-free b32 writes)
        #pragma unroll
        for (int it = 0; it < 8; ++it) {
            int i = tid + it * 256;      // 0..2047
            int r = i & 63;
            int k4 = (i >> 6) * 4;       // 0..124
            int row = row0 + r;
            f4 v = (f4)(0.0f);
            if (row < N) v = *(const f4*)(x + (size_t)row * 128 + k4);
            xT[k4 + 0][r] = v.x; xT[k4 + 1][r] = v.y;
            xT[k4 + 2][r] = v.z; xT[k4 + 3][r] = v.w;
        }
    }
    __syncthreads();

    const int rl = (tid & 15) * 4;    // local rows rl..rl+3
    const int c0 = (tid >> 4) * 4;    // cols c0..c0+3
    f4 acc0 = (f4)(0.0f), acc1 = (f4)(0.0f), acc2 = (f4)(0.0f), acc3 = (f4)(0.0f);
    #pragma unroll 8
    for (int k = 0; k < 128; ++k) {
        f4 xa = *(const f4*)&xT[k][rl];
        f4 wb = *(const f4*)&wS[k][c0];
        acc0 += xa.x * wb;
        acc1 += xa.y * wb;
        acc2 += xa.z * wb;
        acc3 += xa.w * wb;
    }
    #pragma unroll
    for (int i = 0; i < 4; ++i) {
        int row = row0 + rl + i;
        if (row < N) {
            float di = dinv[row];
            f4 a = (i == 0) ? acc0 : (i == 1) ? acc1 : (i == 2) ? acc2 : acc3;
            *(f4*)(hs + (size_t)row * 64 + c0) = a * di;
        }
    }
}

// ---------------- AGG1: h1[i][c] = tanh( dinv[i]*(sum_nb hs[s][c] + hs[i][c]) + b1[c] ), wave per node ----------------
__global__ __launch_bounds__(256) void agg1_k(const float* __restrict__ hs, const int* __restrict__ row_ptr,
                                              const int* __restrict__ cnt, const int* __restrict__ col,
                                              const float* __restrict__ dinv, const float* __restrict__ b1,
                                              float* __restrict__ h1, int N) {
    int wid = blockIdx.x * 4 + (threadIdx.x >> 6);
    int lane = threadIdx.x & 63;
    if (wid >= N) return;
    int beg = row_ptr[wid];
    int num = cnt[wid];
    float acc = 0.0f;
    for (int e0 = 0; e0 < num; e0 += 64) {
        int rem = num - e0;
        int el = 0;
        if (lane < rem) el = col[beg + e0 + lane];
        int m = rem < 64 ? rem : 64;
        int e = 0;
        for (; e + 4 <= m; e += 4) {
            int s0 = __shfl(el, e + 0), s1 = __shfl(el, e + 1);
            int s2 = __shfl(el, e + 2), s3 = __shfl(el, e + 3);
            float v0 = hs[(size_t)s0 * 64 + lane];
            float v1 = hs[(size_t)s1 * 64 + lane];
            float v2 = hs[(size_t)s2 * 64 + lane];
            float v3 = hs[(size_t)s3 * 64 + lane];
            acc += (v0 + v1) + (v2 + v3);
        }
        for (; e < m; ++e) {
            int s = __shfl(el, e);
            acc += hs[(size_t)s * 64 + lane];
        }
    }
    float di = dinv[wid];
    float self = hs[(size_t)wid * 64 + lane];
    h1[(size_t)wid * 64 + lane] = tanhf(di * (acc + self) + b1[lane]);
}

// ---------------- GEMM2: h2s = dinv[r] * (h1 @ W2), [N,64]@[64,16] ----------------
__global__ __launch_bounds__(256) void gemm2_k(const float* __restrict__ h1, const float* __restrict__ W2,
                                               const float* __restrict__ dinv, float* __restrict__ h2s, int N) {
    __shared__ f4 wS[256];   // [k][c4] 64x4
    int tid = threadIdx.x;
    wS[tid] = ((const f4*)W2)[tid];
    __syncthreads();
    int r = blockIdx.x * 256 + tid;
    if (r >= N) return;
    f4 a0 = (f4)(0.0f), a1 = (f4)(0.0f), a2 = (f4)(0.0f), a3 = (f4)(0.0f);
    const float* xr = h1 + (size_t)r * 64;
    #pragma unroll
    for (int k4 = 0; k4 < 16; ++k4) {
        f4 xv = *(const f4*)(xr + k4 * 4);
        #pragma unroll
        for (int kk = 0; kk < 4; ++kk) {
            int k = k4 * 4 + kk;
            float xs = xv[kk];
            a0 += xs * wS[k * 4 + 0];
            a1 += xs * wS[k * 4 + 1];
            a2 += xs * wS[k * 4 + 2];
            a3 += xs * wS[k * 4 + 3];
        }
    }
    float di = dinv[r];
    f4* o = (f4*)(h2s + (size_t)r * 16);
    o[0] = a0 * di; o[1] = a1 * di; o[2] = a2 * di; o[3] = a3 * di;
}

// ---------------- AGG2: 16 channels, quarter-wave per node ----------------
__global__ __launch_bounds__(256) void agg2_k(const float* __restrict__ h2s, const int* __restrict__ row_ptr,
                                              const int* __restrict__ cnt, const int* __restrict__ col,
                                              const float* __restrict__ dinv, const float* __restrict__ b2,
                                              float* __restrict__ h2, int N) {
    int t = blockIdx.x * 256 + threadIdx.x;
    int node = t >> 4;
    int c = t & 15;
    int sub = (threadIdx.x >> 4) & 3;   // quarter within wave
    if (node >= N) return;
    int beg = row_ptr[node];
    int num = cnt[node];
    float acc = 0.0f;
    for (int e0 = 0; e0 < num; e0 += 16) {
        int rem = num - e0;
        int el = 0;
        if (c < rem) el = col[beg + e0 + c];
        int m = rem < 16 ? rem : 16;
        for (int e = 0; e < m; ++e) {
            int s = __shfl(el, (sub << 4) + e);
            acc += h2s[(size_t)s * 16 + c];
        }
    }
    float di = dinv[node];
    float self = h2s[(size_t)node * 16 + c];
    h2[(size_t)node * 16 + c] = tanhf(di * (acc + self) + b2[c]);
}

// ---------------- segmented pool + sigmoid: one block per graph ----------------
__global__ __launch_bounds__(256) void pool_seg_k(const float* __restrict__ h2, const int* __restrict__ gstart,
                                                  float* __restrict__ out) {
    __shared__ float sd[16][16];   // [node-lane][channel]
    int g = blockIdx.x;
    int beg = gstart[g], end = gstart[g + 1];
    int tid = threadIdx.x;
    int c = tid & 15, r = tid >> 4;
    float acc = 0.0f;
    for (int i = beg + r; i < end; i += 16)
        acc += h2[(size_t)i * 16 + c];
    sd[r][c] = acc;
    __syncthreads();
    if (r < 8) sd[r][c] += sd[r + 8][c];
    __syncthreads();
    if (r < 4) sd[r][c] += sd[r + 4][c];
    __syncthreads();
    if (r < 2) sd[r][c] += sd[r + 2][c];
    __syncthreads();
    if (r == 0) {
        float m = (sd[0][c] + sd[1][c]) / fmaxf((float)(end - beg), 1.0f);
        out[g * 16 + c] = 1.0f / (1.0f + expf(-m));
    }
}

extern "C" void kernel_launch(void* const* d_in, const int* in_sizes, int n_in,
                              void* d_out, int out_size, void* d_ws, size_t ws_size,
                              hipStream_t stream) {
    const float* x     = (const float*)d_in[0];
    const int*   ei    = (const int*)d_in[1];
    const int*   batch = (const int*)d_in[2];
    const float* W1    = (const float*)d_in[3];
    const float* b1    = (const float*)d_in[4];
    const float* W2    = (const float*)d_in[5];
    const float* b2    = (const float*)d_in[6];
    float* out = (float*)d_out;

    const int N = in_sizes[2];
    const int E = in_sizes[1] / 2;
    const int G = out_size / 16;
    const int* src = ei;
    const int* dst = ei + E;

    char* w = (char*)d_ws;
    int*   cnt      = (int*)w;    w += (size_t)N * 4;
    int*   row_ptr  = (int*)w;    w += (size_t)N * 4;
    int*   cursor   = (int*)w;    w += (size_t)N * 4;
    float* dinv     = (float*)w;  w += (size_t)N * 4;
    int*   gstart   = (int*)w;    w += (size_t)(G + 1) * 4;
    int*   csums    = (int*)w;    w += 1024;
    int*   col      = (int*)w;    w += (size_t)E * 4;
    float* hs       = (float*)w;  w += (size_t)N * 64 * 4;
    float* h1       = (float*)w;  w += (size_t)N * 64 * 4;
    float* h2s      = (float*)w;  w += (size_t)N * 16 * 4;
    float* h2       = (float*)w;  w += (size_t)N * 16 * 4;

    hipMemsetAsync(cnt, 0, (size_t)N * 4, stream);   // only cnt needs zeroing

    int nch = (N + 1023) / 1024;   // 98 for N=100000 (must be <=256)

    deg_k   <<<(E + 255) / 256, 256, 0, stream>>>(dst, cnt, E);
    dinv_k  <<<(N + 255) / 256, 256, 0, stream>>>(cnt, dinv, N);
    scan_part<<<nch, 256, 0, stream>>>(cnt, csums, N);
    scan_top <<<1, 256, 0, stream>>>(csums, nch);
    scan_chunk<<<nch, 256, 0, stream>>>(cnt, csums, row_ptr, cursor, N);
    fill_k  <<<(E + 255) / 256, 256, 0, stream>>>(src, dst, cursor, col, E);
    gbound_k<<<(N + 255) / 256, 256, 0, stream>>>(batch, gstart, N, G);

    gemm1_k <<<(N + 63) / 64, 256, 0, stream>>>(x, W1, dinv, hs, N);
    agg1_k  <<<(N + 3) / 4, 256, 0, stream>>>(hs, row_ptr, cnt, col, dinv, b1, h1, N);
    gemm2_k <<<(N + 255) / 256, 256, 0, stream>>>(h1, W2, dinv, h2s, N);
    agg2_k  <<<((size_t)N * 16 + 255) / 256, 256, 0, stream>>>(h2s, row_ptr, cnt, col, dinv, b2, h2, N);
    pool_seg_k<<<G, 256, 0, stream>>>(h2, gstart, out);
}

// Round 6
// 236.086 us; speedup vs baseline: 2.0583x; 1.6050x over previous
//
#include <hip/hip_runtime.h>
#include <hip/hip_bf16.h>

typedef float f4 __attribute__((ext_vector_type(4)));

#define BSH 8            // 256 nodes per bucket
#define CHUNK 4096       // edges per sort workgroup
#define CAP 6144         // max edges per bucket (mean 4096, +32 sigma)

// ---------------- pass A: global bucket counts ----------------
__global__ __launch_bounds__(256) void bcount_k(const int* __restrict__ dst, int* __restrict__ bcnt,
                                                int E, int B) {
    __shared__ int hist[512];
    int tid = threadIdx.x;
    for (int i = tid; i < 512; i += 256) hist[i] = 0;
    __syncthreads();
    int base = blockIdx.x * CHUNK;
    int n = min(CHUNK, E - base);
    for (int i = tid; i < n; i += 256) atomicAdd(&hist[dst[base + i] >> BSH], 1);
    __syncthreads();
    for (int i = tid; i < B; i += 256) if (hist[i]) atomicAdd(&bcnt[i], hist[i]);
}

// ---------------- pass B: exclusive scan of bucket counts (B <= 512) ----------------
__global__ __launch_bounds__(256) void bscan_k(const int* __restrict__ bcnt, int* __restrict__ gbase,
                                               int* __restrict__ gcur, int B, int E) {
    __shared__ int sa[512], sb[512];
    int tid = threadIdx.x;
    #pragma unroll
    for (int k = 0; k < 2; ++k) { int i = tid + k * 256; sa[i] = (i < B) ? bcnt[i] : 0; }
    __syncthreads();
    int* c = sa; int* nx = sb;
    for (int off = 1; off < 512; off <<= 1) {
        #pragma unroll
        for (int k = 0; k < 2; ++k) { int i = tid + k * 256; nx[i] = c[i] + (i >= off ? c[i - off] : 0); }
        __syncthreads();
        int* t = c; c = nx; nx = t;
    }
    #pragma unroll
    for (int k = 0; k < 2; ++k) {
        int i = tid + k * 256;
        if (i < B) { int ex = c[i] - bcnt[i]; gbase[i] = ex; gcur[i] = ex; }
    }
    if (tid == 0) gbase[B] = E;
}

// ---------------- pass C: chunked counting sort -> bucket-grouped packed edges ----------------
// bedge[pos] = (src << 8) | (dst & 255), grouped by bucket (dst >> 8). Requires src < 2^24.
__global__ __launch_bounds__(256) void bscat_k(const int* __restrict__ src, const int* __restrict__ dst,
                                               int* __restrict__ gcur, unsigned int* __restrict__ bedge,
                                               int E, int B) {
    __shared__ int hist[512], lbase[512], cur2[512], gb[512];
    __shared__ int sa[512], sb[512];
    __shared__ unsigned int sedge[CHUNK];
    __shared__ unsigned short posb[CHUNK];
    int tid = threadIdx.x;
    int base = blockIdx.x * CHUNK;
    int n = min(CHUNK, E - base);
    for (int i = tid; i < 512; i += 256) hist[i] = 0;
    __syncthreads();
    for (int i = tid; i < n; i += 256) atomicAdd(&hist[dst[base + i] >> BSH], 1);
    __syncthreads();
    // exclusive scan of hist
    #pragma unroll
    for (int k = 0; k < 2; ++k) { int i = tid + k * 256; sa[i] = hist[i]; }
    __syncthreads();
    int* c = sa; int* nx = sb;
    for (int off = 1; off < 512; off <<= 1) {
        #pragma unroll
        for (int k = 0; k < 2; ++k) { int i = tid + k * 256; nx[i] = c[i] + (i >= off ? c[i - off] : 0); }
        __syncthreads();
        int* t = c; c = nx; nx = t;
    }
    #pragma unroll
    for (int k = 0; k < 2; ++k) {
        int i = tid + k * 256;
        int ex = c[i] - hist[i];
        lbase[i] = ex; cur2[i] = ex;
        if (i < B) gb[i] = hist[i] ? atomicAdd(&gcur[i], hist[i]) : 0;
    }
    // position -> bucket map (each thread owns slots tid, tid+256: no cross-thread deps yet)
    for (int t = tid; t < B; t += 256) {
        int e0 = lbase[t], e1 = e0 + hist[t];
        for (int j = e0; j < e1; ++j) posb[j] = (unsigned short)t;
    }
    __syncthreads();
    // scatter into LDS, sorted by bucket
    for (int i = tid; i < n; i += 256) {
        int d = dst[base + i];
        int s = src[base + i];
        int b = d >> BSH;
        int p = atomicAdd(&cur2[b], 1);
        sedge[p] = ((unsigned int)s << BSH) | (unsigned int)(d & ((1 << BSH) - 1));
    }
    __syncthreads();
    // coalesced run flush
    for (int i = tid; i < n; i += 256) {
        int b = posb[i];
        bedge[gb[b] + (i - lbase[b])] = sedge[i];
    }
}

// ---------------- pass D: per-bucket CSR + degrees + dinv, all coalesced ----------------
__global__ __launch_bounds__(256) void bcsr_k(const unsigned int* __restrict__ bedge,
                                              const int* __restrict__ gbase,
                                              int* __restrict__ row_ptr, int* __restrict__ cnt,
                                              float* __restrict__ dinv, int* __restrict__ col,
                                              int N, int B) {
    __shared__ int hist[256], lofs[256], cur2[256];
    __shared__ int sa[256], sb[256];
    __shared__ int cols[CAP];
    int b = blockIdx.x, tid = threadIdx.x;
    int node0 = b << BSH;
    int g0 = gbase[b], g1 = gbase[b + 1];
    int n = g1 - g0;
    hist[tid] = 0;
    __syncthreads();
    for (int i = tid; i < n; i += 256) atomicAdd(&hist[bedge[g0 + i] & 255], 1);
    __syncthreads();
    sa[tid] = hist[tid];
    __syncthreads();
    int* c = sa; int* nx = sb;
    for (int off = 1; off < 256; off <<= 1) {
        nx[tid] = c[tid] + (tid >= off ? c[tid - off] : 0);
        __syncthreads();
        int* t = c; c = nx; nx = t;
    }
    int ex = c[tid] - hist[tid];
    lofs[tid] = ex; cur2[tid] = ex;
    int node = node0 + tid;
    if (node < N) {
        int deg = hist[tid];
        cnt[node] = deg;
        row_ptr[node] = g0 + ex;
        dinv[node] = rsqrtf((float)(deg + 1));
    }
    __syncthreads();
    for (int i = tid; i < n; i += 256) {
        unsigned int e = bedge[g0 + i];
        int p = atomicAdd(&cur2[e & 255], 1);
        if (p < CAP) cols[p] = (int)(e >> BSH);
    }
    __syncthreads();
    for (int i = tid; i < n; i += 256) col[g0 + i] = (i < CAP) ? cols[i] : 0;
}

// ---------------- graph boundaries from sorted batch ----------------
__global__ __launch_bounds__(256) void gbound_k(const int* __restrict__ batch, int* __restrict__ gstart,
                                                int N, int G) {
    int i = blockIdx.x * 256 + threadIdx.x;
    if (i >= N) return;
    int b = batch[i];
    int prev = (i == 0) ? -1 : batch[i - 1];
    for (int g = prev + 1; g <= b; ++g) gstart[g] = i;
    if (i == N - 1) {
        for (int g = b + 1; g <= G; ++g) gstart[g] = N;
    }
}

// ---------------- GEMM1: hs = dinv[r] * (x @ W1),  [N,128]@[128,64] ----------------
__global__ __launch_bounds__(256) void gemm1_k(const float* __restrict__ x, const float* __restrict__ W1,
                                               const float* __restrict__ dinv, float* __restrict__ hs, int N) {
    __shared__ float xT[128][64];   // k-major x tile
    __shared__ float wS[128][64];
    const int tid = threadIdx.x;
    const int row0 = blockIdx.x * 64;

    {   // W1: 8192 floats = 2048 f4, contiguous
        const f4* wsrc = (const f4*)W1;
        f4* wdst = (f4*)&wS[0][0];
        #pragma unroll
        for (int i = 0; i < 8; ++i) wdst[tid + i * 256] = wsrc[tid + i * 256];
    }
    {   // x tile rows row0..row0+63, transposed into LDS
        #pragma unroll
        for (int it = 0; it < 8; ++it) {
            int i = tid + it * 256;      // 0..2047
            int r = i & 63;
            int k4 = (i >> 6) * 4;       // 0..124
            int row = row0 + r;
            f4 v = (f4)(0.0f);
            if (row < N) v = *(const f4*)(x + (size_t)row * 128 + k4);
            xT[k4 + 0][r] = v.x; xT[k4 + 1][r] = v.y;
            xT[k4 + 2][r] = v.z; xT[k4 + 3][r] = v.w;
        }
    }
    __syncthreads();

    const int rl = (tid & 15) * 4;    // local rows rl..rl+3
    const int c0 = (tid >> 4) * 4;    // cols c0..c0+3
    f4 acc0 = (f4)(0.0f), acc1 = (f4)(0.0f), acc2 = (f4)(0.0f), acc3 = (f4)(0.0f);
    #pragma unroll 8
    for (int k = 0; k < 128; ++k) {
        f4 xa = *(const f4*)&xT[k][rl];
        f4 wb = *(const f4*)&wS[k][c0];
        acc0 += xa.x * wb;
        acc1 += xa.y * wb;
        acc2 += xa.z * wb;
        acc3 += xa.w * wb;
    }
    #pragma unroll
    for (int i = 0; i < 4; ++i) {
        int row = row0 + rl + i;
        if (row < N) {
            float di = dinv[row];
            f4 a = (i == 0) ? acc0 : (i == 1) ? acc1 : (i == 2) ? acc2 : acc3;
            *(f4*)(hs + (size_t)row * 64 + c0) = a * di;
        }
    }
}

// ---------------- AGG1: h1[i][c] = tanh( dinv[i]*(sum_nb hs[s][c] + hs[i][c]) + b1[c] ) ----------------
__global__ __launch_bounds__(256) void agg1_k(const float* __restrict__ hs, const int* __restrict__ row_ptr,
                                              const int* __restrict__ cnt, const int* __restrict__ col,
                                              const float* __restrict__ dinv, const float* __restrict__ b1,
                                              float* __restrict__ h1, int N) {
    int wid = blockIdx.x * 4 + (threadIdx.x >> 6);
    int lane = threadIdx.x & 63;
    if (wid >= N) return;
    int beg = row_ptr[wid];
    int num = cnt[wid];
    float acc = 0.0f;
    for (int e0 = 0; e0 < num; e0 += 64) {
        int rem = num - e0;
        int el = 0;
        if (lane < rem) el = col[beg + e0 + lane];
        int m = rem < 64 ? rem : 64;
        int e = 0;
        for (; e + 4 <= m; e += 4) {
            int s0 = __shfl(el, e + 0), s1 = __shfl(el, e + 1);
            int s2 = __shfl(el, e + 2), s3 = __shfl(el, e + 3);
            float v0 = hs[(size_t)s0 * 64 + lane];
            float v1 = hs[(size_t)s1 * 64 + lane];
            float v2 = hs[(size_t)s2 * 64 + lane];
            float v3 = hs[(size_t)s3 * 64 + lane];
            acc += (v0 + v1) + (v2 + v3);
        }
        for (; e < m; ++e) {
            int s = __shfl(el, e);
            acc += hs[(size_t)s * 64 + lane];
        }
    }
    float di = dinv[wid];
    float self = hs[(size_t)wid * 64 + lane];
    h1[(size_t)wid * 64 + lane] = tanhf(di * (acc + self) + b1[lane]);
}

// ---------------- GEMM2: h2s = dinv[r] * (h1 @ W2), [N,64]@[64,16] ----------------
__global__ __launch_bounds__(256) void gemm2_k(const float* __restrict__ h1, const float* __restrict__ W2,
                                               const float* __restrict__ dinv, float* __restrict__ h2s, int N) {
    __shared__ f4 wS[256];   // [k][c4] 64x4
    int tid = threadIdx.x;
    wS[tid] = ((const f4*)W2)[tid];
    __syncthreads();
    int r = blockIdx.x * 256 + tid;
    if (r >= N) return;
    f4 a0 = (f4)(0.0f), a1 = (f4)(0.0f), a2 = (f4)(0.0f), a3 = (f4)(0.0f);
    const float* xr = h1 + (size_t)r * 64;
    #pragma unroll
    for (int k4 = 0; k4 < 16; ++k4) {
        f4 xv = *(const f4*)(xr + k4 * 4);
        #pragma unroll
        for (int kk = 0; kk < 4; ++kk) {
            int k = k4 * 4 + kk;
            float xs = xv[kk];
            a0 += xs * wS[k * 4 + 0];
            a1 += xs * wS[k * 4 + 1];
            a2 += xs * wS[k * 4 + 2];
            a3 += xs * wS[k * 4 + 3];
        }
    }
    float di = dinv[r];
    f4* o = (f4*)(h2s + (size_t)r * 16);
    o[0] = a0 * di; o[1] = a1 * di; o[2] = a2 * di; o[3] = a3 * di;
}

// ---------------- AGG2: 16 channels, quarter-wave per node ----------------
__global__ __launch_bounds__(256) void agg2_k(const float* __restrict__ h2s, const int* __restrict__ row_ptr,
                                              const int* __restrict__ cnt, const int* __restrict__ col,
                                              const float* __restrict__ dinv, const float* __restrict__ b2,
                                              float* __restrict__ h2, int N) {
    int t = blockIdx.x * 256 + threadIdx.x;
    int node = t >> 4;
    int c = t & 15;
    int sub = (threadIdx.x >> 4) & 3;   // quarter within wave
    if (node >= N) return;
    int beg = row_ptr[node];
    int num = cnt[node];
    float acc = 0.0f;
    for (int e0 = 0; e0 < num; e0 += 16) {
        int rem = num - e0;
        int el = 0;
        if (c < rem) el = col[beg + e0 + c];
        int m = rem < 16 ? rem : 16;
        for (int e = 0; e < m; ++e) {
            int s = __shfl(el, (sub << 4) + e);
            acc += h2s[(size_t)s * 16 + c];
        }
    }
    float di = dinv[node];
    float self = h2s[(size_t)node * 16 + c];
    h2[(size_t)node * 16 + c] = tanhf(di * (acc + self) + b2[c]);
}

// ---------------- segmented pool + sigmoid: one block per graph ----------------
__global__ __launch_bounds__(256) void pool_seg_k(const float* __restrict__ h2, const int* __restrict__ gstart,
                                                  float* __restrict__ out) {
    __shared__ float sd[16][16];   // [node-lane][channel]
    int g = blockIdx.x;
    int beg = gstart[g], end = gstart[g + 1];
    int tid = threadIdx.x;
    int c = tid & 15, r = tid >> 4;
    float acc = 0.0f;
    for (int i = beg + r; i < end; i += 16)
        acc += h2[(size_t)i * 16 + c];
    sd[r][c] = acc;
    __syncthreads();
    if (r < 8) sd[r][c] += sd[r + 8][c];
    __syncthreads();
    if (r < 4) sd[r][c] += sd[r + 4][c];
    __syncthreads();
    if (r < 2) sd[r][c] += sd[r + 2][c];
    __syncthreads();
    if (r == 0) {
        float m = (sd[0][c] + sd[1][c]) / fmaxf((float)(end - beg), 1.0f);
        out[g * 16 + c] = 1.0f / (1.0f + expf(-m));
    }
}

extern "C" void kernel_launch(void* const* d_in, const int* in_sizes, int n_in,
                              void* d_out, int out_size, void* d_ws, size_t ws_size,
                              hipStream_t stream) {
    const float* x     = (const float*)d_in[0];
    const int*   ei    = (const int*)d_in[1];
    const int*   batch = (const int*)d_in[2];
    const float* W1    = (const float*)d_in[3];
    const float* b1    = (const float*)d_in[4];
    const float* W2    = (const float*)d_in[5];
    const float* b2    = (const float*)d_in[6];
    float* out = (float*)d_out;

    const int N = in_sizes[2];
    const int E = in_sizes[1] / 2;
    const int G = out_size / 16;
    const int* src = ei;
    const int* dst = ei + E;

    const int B = (N + 255) >> 8;              // 391 buckets (must be <= 512)
    const int nchunk = (E + CHUNK - 1) / CHUNK;

    char* w = (char*)d_ws;
    int*   bcnt     = (int*)w;    w += 512 * 4;
    int*   gbase    = (int*)w;    w += 520 * 4;
    int*   gcur     = (int*)w;    w += 512 * 4;
    int*   row_ptr  = (int*)w;    w += (size_t)N * 4;
    int*   cnt      = (int*)w;    w += (size_t)N * 4;
    float* dinv     = (float*)w;  w += (size_t)N * 4;
    int*   gstart   = (int*)w;    w += (size_t)(G + 1) * 4;
    int*   col      = (int*)w;    w += (size_t)E * 4;
    float* hs       = (float*)w;  w += (size_t)N * 64 * 4;
    float* h1       = (float*)w;  w += (size_t)N * 64 * 4;
    float* h2s      = (float*)w;  w += (size_t)N * 16 * 4;
    float* h2       = (float*)w;  w += (size_t)N * 16 * 4;
    // bedge (E uints) is dead before agg1_k writes h1 -> overlay on h1
    unsigned int* bedge = (unsigned int*)h1;

    hipMemsetAsync(bcnt, 0, 512 * 4, stream);

    bcount_k<<<nchunk, 256, 0, stream>>>(dst, bcnt, E, B);
    bscan_k <<<1, 256, 0, stream>>>(bcnt, gbase, gcur, B, E);
    bscat_k <<<nchunk, 256, 0, stream>>>(src, dst, gcur, bedge, E, B);
    bcsr_k  <<<B, 256, 0, stream>>>(bedge, gbase, row_ptr, cnt, dinv, col, N, B);
    gbound_k<<<(N + 255) / 256, 256, 0, stream>>>(batch, gstart, N, G);

    gemm1_k <<<(N + 63) / 64, 256, 0, stream>>>(x, W1, dinv, hs, N);
    agg1_k  <<<(N + 3) / 4, 256, 0, stream>>>(hs, row_ptr, cnt, col, dinv, b1, h1, N);
    gemm2_k <<<(N + 255) / 256, 256, 0, stream>>>(h1, W2, dinv, h2s, N);
    agg2_k  <<<((size_t)N * 16 + 255) / 256, 256, 0, stream>>>(h2s, row_ptr, cnt, col, dinv, b2, h2, N);
    pool_seg_k<<<G, 256, 0, stream>>>(h2, gstart, out);
}

// Round 8
// 215.436 us; speedup vs baseline: 2.2556x; 1.0959x over previous
//
#include <hip/hip_runtime.h>
#include <hip/hip_bf16.h>

typedef float f4 __attribute__((ext_vector_type(4)));
typedef unsigned short us;
typedef unsigned int uint32;

__device__ inline float bf2f(us u) {
    union { uint32 i; float f; } x; x.i = ((uint32)u) << 16; return x.f;
}
__device__ inline uint32 f2bf(float f) {   // RNE
    union { float f; uint32 i; } x; x.f = f;
    return (x.i + 0x7fffu + ((x.i >> 16) & 1u)) >> 16;
}

#define BSH 8            // 256 nodes per bucket
#define CHUNK 4096       // edges per sort workgroup
#define CAP 6144         // max edges per bucket (mean 4096, +32 sigma)

// ---------------- pass A: global bucket counts ----------------
__global__ __launch_bounds__(256) void bcount_k(const int* __restrict__ dst, int* __restrict__ bcnt,
                                                int E, int B) {
    __shared__ int hist[512];
    int tid = threadIdx.x;
    for (int i = tid; i < 512; i += 256) hist[i] = 0;
    __syncthreads();
    int base = blockIdx.x * CHUNK;
    int n = min(CHUNK, E - base);
    for (int i = tid; i < n; i += 256) atomicAdd(&hist[dst[base + i] >> BSH], 1);
    __syncthreads();
    for (int i = tid; i < B; i += 256) if (hist[i]) atomicAdd(&bcnt[i], hist[i]);
}

// ---------------- pass B: exclusive scan of bucket counts (B <= 512) ----------------
__global__ __launch_bounds__(256) void bscan_k(const int* __restrict__ bcnt, int* __restrict__ gbase,
                                               int* __restrict__ gcur, int B, int E) {
    __shared__ int sa[512], sb[512];
    int tid = threadIdx.x;
    #pragma unroll
    for (int k = 0; k < 2; ++k) { int i = tid + k * 256; sa[i] = (i < B) ? bcnt[i] : 0; }
    __syncthreads();
    int* c = sa; int* nx = sb;
    for (int off = 1; off < 512; off <<= 1) {
        #pragma unroll
        for (int k = 0; k < 2; ++k) { int i = tid + k * 256; nx[i] = c[i] + (i >= off ? c[i - off] : 0); }
        __syncthreads();
        int* t = c; c = nx; nx = t;
    }
    #pragma unroll
    for (int k = 0; k < 2; ++k) {
        int i = tid + k * 256;
        if (i < B) { int ex = c[i] - bcnt[i]; gbase[i] = ex; gcur[i] = ex; }
    }
    if (tid == 0) gbase[B] = E;
}

// ---------------- pass C: chunked counting sort -> bucket-grouped packed edges ----------------
// bedge[pos] = (src << 8) | (dst & 255), grouped by bucket (dst >> 8). Requires src < 2^24.
__global__ __launch_bounds__(256) void bscat_k(const int* __restrict__ src, const int* __restrict__ dst,
                                               int* __restrict__ gcur, unsigned int* __restrict__ bedge,
                                               int E, int B) {
    __shared__ int hist[512], lbase[512], cur2[512], gb[512];
    __shared__ int sa[512], sb[512];
    __shared__ unsigned int sedge[CHUNK];
    __shared__ unsigned short posb[CHUNK];
    int tid = threadIdx.x;
    int base = blockIdx.x * CHUNK;
    int n = min(CHUNK, E - base);
    for (int i = tid; i < 512; i += 256) hist[i] = 0;
    __syncthreads();
    for (int i = tid; i < n; i += 256) atomicAdd(&hist[dst[base + i] >> BSH], 1);
    __syncthreads();
    #pragma unroll
    for (int k = 0; k < 2; ++k) { int i = tid + k * 256; sa[i] = hist[i]; }
    __syncthreads();
    int* c = sa; int* nx = sb;
    for (int off = 1; off < 512; off <<= 1) {
        #pragma unroll
        for (int k = 0; k < 2; ++k) { int i = tid + k * 256; nx[i] = c[i] + (i >= off ? c[i - off] : 0); }
        __syncthreads();
        int* t = c; c = nx; nx = t;
    }
    #pragma unroll
    for (int k = 0; k < 2; ++k) {
        int i = tid + k * 256;
        int ex = c[i] - hist[i];
        lbase[i] = ex; cur2[i] = ex;
        if (i < B) gb[i] = hist[i] ? atomicAdd(&gcur[i], hist[i]) : 0;
    }
    for (int t = tid; t < B; t += 256) {
        int e0 = lbase[t], e1 = e0 + hist[t];
        for (int j = e0; j < e1; ++j) posb[j] = (unsigned short)t;
    }
    __syncthreads();
    for (int i = tid; i < n; i += 256) {
        int d = dst[base + i];
        int s = src[base + i];
        int b = d >> BSH;
        int p = atomicAdd(&cur2[b], 1);
        sedge[p] = ((unsigned int)s << BSH) | (unsigned int)(d & ((1 << BSH) - 1));
    }
    __syncthreads();
    for (int i = tid; i < n; i += 256) {
        int b = posb[i];
        bedge[gb[b] + (i - lbase[b])] = sedge[i];
    }
}

// ---------------- pass D: per-bucket CSR + degrees + dinv, all coalesced ----------------
__global__ __launch_bounds__(256) void bcsr_k(const unsigned int* __restrict__ bedge,
                                              const int* __restrict__ gbase,
                                              int* __restrict__ row_ptr, int* __restrict__ cnt,
                                              float* __restrict__ dinv, int* __restrict__ col,
                                              int N, int B) {
    __shared__ int hist[256], lofs[256], cur2[256];
    __shared__ int sa[256], sb[256];
    __shared__ int cols[CAP];
    int b = blockIdx.x, tid = threadIdx.x;
    int node0 = b << BSH;
    int g0 = gbase[b], g1 = gbase[b + 1];
    int n = g1 - g0;
    hist[tid] = 0;
    __syncthreads();
    for (int i = tid; i < n; i += 256) atomicAdd(&hist[bedge[g0 + i] & 255], 1);
    __syncthreads();
    sa[tid] = hist[tid];
    __syncthreads();
    int* c = sa; int* nx = sb;
    for (int off = 1; off < 256; off <<= 1) {
        nx[tid] = c[tid] + (tid >= off ? c[tid - off] : 0);
        __syncthreads();
        int* t = c; c = nx; nx = t;
    }
    int ex = c[tid] - hist[tid];
    lofs[tid] = ex; cur2[tid] = ex;
    int node = node0 + tid;
    if (node < N) {
        int deg = hist[tid];
        cnt[node] = deg;
        row_ptr[node] = g0 + ex;
        dinv[node] = rsqrtf((float)(deg + 1));
    }
    __syncthreads();
    for (int i = tid; i < n; i += 256) {
        unsigned int e = bedge[g0 + i];
        int p = atomicAdd(&cur2[e & 255], 1);
        if (p < CAP) cols[p] = (int)(e >> BSH);
    }
    __syncthreads();
    for (int i = tid; i < n; i += 256) col[g0 + i] = (i < CAP) ? cols[i] : 0;
}

// ---------------- graph boundaries from sorted batch ----------------
__global__ __launch_bounds__(256) void gbound_k(const int* __restrict__ batch, int* __restrict__ gstart,
                                                int N, int G) {
    int i = blockIdx.x * 256 + threadIdx.x;
    if (i >= N) return;
    int b = batch[i];
    int prev = (i == 0) ? -1 : batch[i - 1];
    for (int g = prev + 1; g <= b; ++g) gstart[g] = i;
    if (i == N - 1) {
        for (int g = b + 1; g <= G; ++g) gstart[g] = N;
    }
}

// ---------------- GEMM1: hs_bf = bf16( dinv[r] * (x @ W1) ),  [N,128]@[128,64] ----------------
__global__ __launch_bounds__(256) void gemm1_k(const float* __restrict__ x, const float* __restrict__ W1,
                                               const float* __restrict__ dinv, us* __restrict__ hsb, int N) {
    __shared__ float xT[128][64];   // k-major x tile
    __shared__ float wS[128][64];
    const int tid = threadIdx.x;
    const int row0 = blockIdx.x * 64;

    {   // W1: 8192 floats = 2048 f4, contiguous
        const f4* wsrc = (const f4*)W1;
        f4* wdst = (f4*)&wS[0][0];
        #pragma unroll
        for (int i = 0; i < 8; ++i) wdst[tid + i * 256] = wsrc[tid + i * 256];
    }
    {   // x tile rows row0..row0+63, transposed into LDS
        #pragma unroll
        for (int it = 0; it < 8; ++it) {
            int i = tid + it * 256;      // 0..2047
            int r = i & 63;
            int k4 = (i >> 6) * 4;       // 0..124
            int row = row0 + r;
            f4 v = (f4)(0.0f);
            if (row < N) v = *(const f4*)(x + (size_t)row * 128 + k4);
            xT[k4 + 0][r] = v.x; xT[k4 + 1][r] = v.y;
            xT[k4 + 2][r] = v.z; xT[k4 + 3][r] = v.w;
        }
    }
    __syncthreads();

    const int rl = (tid & 15) * 4;    // local rows rl..rl+3
    const int c0 = (tid >> 4) * 4;    // cols c0..c0+3
    f4 acc0 = (f4)(0.0f), acc1 = (f4)(0.0f), acc2 = (f4)(0.0f), acc3 = (f4)(0.0f);
    #pragma unroll 8
    for (int k = 0; k < 128; ++k) {
        f4 xa = *(const f4*)&xT[k][rl];
        f4 wb = *(const f4*)&wS[k][c0];
        acc0 += xa.x * wb;
        acc1 += xa.y * wb;
        acc2 += xa.z * wb;
        acc3 += xa.w * wb;
    }
    #pragma unroll
    for (int i = 0; i < 4; ++i) {
        int row = row0 + rl + i;
        if (row < N) {
            float di = dinv[row];
            f4 a = (i == 0) ? acc0 : (i == 1) ? acc1 : (i == 2) ? acc2 : acc3;
            a *= di;
            uint2 p;
            p.x = f2bf(a.x) | (f2bf(a.y) << 16);
            p.y = f2bf(a.z) | (f2bf(a.w) << 16);
            *(uint2*)(hsb + (size_t)row * 64 + c0) = p;
        }
    }
}

// ---------------- AGG1: h1[i][c] = tanh( dinv[i]*(sum_nb hsb[s][c] + hsb[i][c]) + b1[c] ) ----------------
__global__ __launch_bounds__(256) void agg1_k(const us* __restrict__ hsb, const int* __restrict__ row_ptr,
                                              const int* __restrict__ cnt, const int* __restrict__ col,
                                              const float* __restrict__ dinv, const float* __restrict__ b1,
                                              float* __restrict__ h1, int N) {
    int wid = blockIdx.x * 4 + (threadIdx.x >> 6);
    int lane = threadIdx.x & 63;
    if (wid >= N) return;
    int beg = row_ptr[wid];
    int num = cnt[wid];
    float acc = 0.0f;
    for (int e0 = 0; e0 < num; e0 += 64) {
        int rem = num - e0;
        int el = 0;
        if (lane < rem) el = col[beg + e0 + lane];
        int m = rem < 64 ? rem : 64;
        int e = 0;
        for (; e + 4 <= m; e += 4) {
            int s0 = __shfl(el, e + 0), s1 = __shfl(el, e + 1);
            int s2 = __shfl(el, e + 2), s3 = __shfl(el, e + 3);
            float v0 = bf2f(hsb[(size_t)s0 * 64 + lane]);
            float v1 = bf2f(hsb[(size_t)s1 * 64 + lane]);
            float v2 = bf2f(hsb[(size_t)s2 * 64 + lane]);
            float v3 = bf2f(hsb[(size_t)s3 * 64 + lane]);
            acc += (v0 + v1) + (v2 + v3);
        }
        for (; e < m; ++e) {
            int s = __shfl(el, e);
            acc += bf2f(hsb[(size_t)s * 64 + lane]);
        }
    }
    float di = dinv[wid];
    float self = bf2f(hsb[(size_t)wid * 64 + lane]);
    h1[(size_t)wid * 64 + lane] = tanhf(di * (acc + self) + b1[lane]);
}

// ---------------- GEMM2: h2s = dinv[r] * (h1 @ W2), [N,64]@[64,16] ----------------
__global__ __launch_bounds__(256) void gemm2_k(const float* __restrict__ h1, const float* __restrict__ W2,
                                               const float* __restrict__ dinv, float* __restrict__ h2s, int N) {
    __shared__ f4 wS[256];   // [k][c4] 64x4
    int tid = threadIdx.x;
    wS[tid] = ((const f4*)W2)[tid];
    __syncthreads();
    int r = blockIdx.x * 256 + tid;
    if (r >= N) return;
    f4 a0 = (f4)(0.0f), a1 = (f4)(0.0f), a2 = (f4)(0.0f), a3 = (f4)(0.0f);
    const float* xr = h1 + (size_t)r * 64;
    #pragma unroll
    for (int k4 = 0; k4 < 16; ++k4) {
        f4 xv = *(const f4*)(xr + k4 * 4);
        #pragma unroll
        for (int kk = 0; kk < 4; ++kk) {
            int k = k4 * 4 + kk;
            float xs = xv[kk];
            a0 += xs * wS[k * 4 + 0];
            a1 += xs * wS[k * 4 + 1];
            a2 += xs * wS[k * 4 + 2];
            a3 += xs * wS[k * 4 + 3];
        }
    }
    float di = dinv[r];
    f4* o = (f4*)(h2s + (size_t)r * 16);
    o[0] = a0 * di; o[1] = a1 * di; o[2] = a2 * di; o[3] = a3 * di;
}

// ---------------- AGG2: 16 channels, quarter-wave per node ----------------
__global__ __launch_bounds__(256) void agg2_k(const float* __restrict__ h2s, const int* __restrict__ row_ptr,
                                              const int* __restrict__ cnt, const int* __restrict__ col,
                                              const float* __restrict__ dinv, const float* __restrict__ b2,
                                              float* __restrict__ h2, int N) {
    int t = blockIdx.x * 256 + threadIdx.x;
    int node = t >> 4;
    int c = t & 15;
    int sub = (threadIdx.x >> 4) & 3;   // quarter within wave
    if (node >= N) return;
    int beg = row_ptr[node];
    int num = cnt[node];
    float acc = 0.0f;
    for (int e0 = 0; e0 < num; e0 += 16) {
        int rem = num - e0;
        int el = 0;
        if (c < rem) el = col[beg + e0 + c];
        int m = rem < 16 ? rem : 16;
        for (int e = 0; e < m; ++e) {
            int s = __shfl(el, (sub << 4) + e);
            acc += h2s[(size_t)s * 16 + c];
        }
    }
    float di = dinv[node];
    float self = h2s[(size_t)node * 16 + c];
    h2[(size_t)node * 16 + c] = tanhf(di * (acc + self) + b2[c]);
}

// ---------------- segmented pool + sigmoid: one block per graph ----------------
__global__ __launch_bounds__(256) void pool_seg_k(const float* __restrict__ h2, const int* __restrict__ gstart,
                                                  float* __restrict__ out) {
    __shared__ float sd[16][16];   // [node-lane][channel]
    int g = blockIdx.x;
    int beg = gstart[g], end = gstart[g + 1];
    int tid = threadIdx.x;
    int c = tid & 15, r = tid >> 4;
    float acc = 0.0f;
    for (int i = beg + r; i < end; i += 16)
        acc += h2[(size_t)i * 16 + c];
    sd[r][c] = acc;
    __syncthreads();
    if (r < 8) sd[r][c] += sd[r + 8][c];
    __syncthreads();
    if (r < 4) sd[r][c] += sd[r + 4][c];
    __syncthreads();
    if (r < 2) sd[r][c] += sd[r + 2][c];
    __syncthreads();
    if (r == 0) {
        float m = (sd[0][c] + sd[1][c]) / fmaxf((float)(end - beg), 1.0f);
        out[g * 16 + c] = 1.0f / (1.0f + expf(-m));
    }
}

extern "C" void kernel_launch(void* const* d_in, const int* in_sizes, int n_in,
                              void* d_out, int out_size, void* d_ws, size_t ws_size,
                              hipStream_t stream) {
    const float* x     = (const float*)d_in[0];
    const int*   ei    = (const int*)d_in[1];
    const int*   batch = (const int*)d_in[2];
    const float* W1    = (const float*)d_in[3];
    const float* b1    = (const float*)d_in[4];
    const float* W2    = (const float*)d_in[5];
    const float* b2    = (const float*)d_in[6];
    float* out = (float*)d_out;

    const int N = in_sizes[2];
    const int E = in_sizes[1] / 2;
    const int G = out_size / 16;
    const int* src = ei;
    const int* dst = ei + E;

    const int B = (N + 255) >> 8;              // 391 buckets (must be <= 512)
    const int nchunk = (E + CHUNK - 1) / CHUNK;

    char* w = (char*)d_ws;
    int*   bcnt     = (int*)w;    w += 512 * 4;
    int*   gbase    = (int*)w;    w += 520 * 4;
    int*   gcur     = (int*)w;    w += 512 * 4;
    int*   row_ptr  = (int*)w;    w += (size_t)N * 4;
    int*   cnt      = (int*)w;    w += (size_t)N * 4;
    float* dinv     = (float*)w;  w += (size_t)N * 4;
    int*   gstart   = (int*)w;    w += (size_t)(G + 1) * 4;
    int*   col      = (int*)w;    w += (size_t)E * 4;
    us*    hsb      = (us*)w;     w += (size_t)N * 64 * 2;
    float* h1       = (float*)w;  w += (size_t)N * 64 * 4;
    float* h2s      = (float*)w;  w += (size_t)N * 16 * 4;
    float* h2       = (float*)w;  w += (size_t)N * 16 * 4;
    // bedge (E uints) is dead before agg1_k writes h1 -> overlay on h1
    unsigned int* bedge = (unsigned int*)h1;

    hipMemsetAsync(bcnt, 0, 512 * 4, stream);

    bcount_k<<<nchunk, 256, 0, stream>>>(dst, bcnt, E, B);
    bscan_k <<<1, 256, 0, stream>>>(bcnt, gbase, gcur, B, E);
    bscat_k <<<nchunk, 256, 0, stream>>>(src, dst, gcur, bedge, E, B);
    bcsr_k  <<<B, 256, 0, stream>>>(bedge, gbase, row_ptr, cnt, dinv, col, N, B);
    gbound_k<<<(N + 255) / 256, 256, 0, stream>>>(batch, gstart, N, G);

    gemm1_k <<<(N + 63) / 64, 256, 0, stream>>>(x, W1, dinv, hsb, N);
    agg1_k  <<<(N + 3) / 4, 256, 0, stream>>>(hsb, row_ptr, cnt, col, dinv, b1, h1, N);
    gemm2_k <<<(N + 255) / 256, 256, 0, stream>>>(h1, W2, dinv, h2s, N);
    agg2_k  <<<((size_t)N * 16 + 255) / 256, 256, 0, stream>>>(h2s, row_ptr, cnt, col, dinv, b2, h2, N);
    pool_seg_k<<<G, 256, 0, stream>>>(h2, gstart, out);
}

// Round 9
// 197.182 us; speedup vs baseline: 2.4644x; 1.0926x over previous
//
#include <hip/hip_runtime.h>
#include <hip/hip_bf16.h>

typedef float f4 __attribute__((ext_vector_type(4)));
typedef unsigned short us;
typedef unsigned int uint32;

__device__ inline float bf2f(us u) {
    union { uint32 i; float f; } x; x.i = ((uint32)u) << 16; return x.f;
}
__device__ inline uint32 f2bf(float f) {   // RNE
    union { float f; uint32 i; } x; x.f = f;
    return (x.i + 0x7fffu + ((x.i >> 16) & 1u)) >> 16;
}

#define BSH 8            // 256 nodes per bucket
#define CHUNK 4096       // edges per sort workgroup
#define CAP 6144         // max edges per bucket (mean 4096, +32 sigma)

// ---------------- pass A: global bucket counts ----------------
__global__ __launch_bounds__(256) void bcount_k(const int* __restrict__ dst, int* __restrict__ bcnt,
                                                int E, int B) {
    __shared__ int hist[512];
    int tid = threadIdx.x;
    for (int i = tid; i < 512; i += 256) hist[i] = 0;
    __syncthreads();
    int base = blockIdx.x * CHUNK;
    int n = min(CHUNK, E - base);
    for (int i = tid; i < n; i += 256) atomicAdd(&hist[dst[base + i] >> BSH], 1);
    __syncthreads();
    for (int i = tid; i < B; i += 256) if (hist[i]) atomicAdd(&bcnt[i], hist[i]);
}

// ---------------- pass B: exclusive scan of bucket counts (B <= 512) ----------------
__global__ __launch_bounds__(256) void bscan_k(const int* __restrict__ bcnt, int* __restrict__ gbase,
                                               int* __restrict__ gcur, int B, int E) {
    __shared__ int sa[512], sb[512];
    int tid = threadIdx.x;
    #pragma unroll
    for (int k = 0; k < 2; ++k) { int i = tid + k * 256; sa[i] = (i < B) ? bcnt[i] : 0; }
    __syncthreads();
    int* c = sa; int* nx = sb;
    for (int off = 1; off < 512; off <<= 1) {
        #pragma unroll
        for (int k = 0; k < 2; ++k) { int i = tid + k * 256; nx[i] = c[i] + (i >= off ? c[i - off] : 0); }
        __syncthreads();
        int* t = c; c = nx; nx = t;
    }
    #pragma unroll
    for (int k = 0; k < 2; ++k) {
        int i = tid + k * 256;
        if (i < B) { int ex = c[i] - bcnt[i]; gbase[i] = ex; gcur[i] = ex; }
    }
    if (tid == 0) gbase[B] = E;
}

// ---------------- pass C: chunked counting sort -> bucket-grouped packed edges ----------------
// bedge[pos] = (src << 8) | (dst & 255), grouped by bucket (dst >> 8). Requires src < 2^24.
__global__ __launch_bounds__(256) void bscat_k(const int* __restrict__ src, const int* __restrict__ dst,
                                               int* __restrict__ gcur, unsigned int* __restrict__ bedge,
                                               int E, int B) {
    __shared__ int hist[512], lbase[512], cur2[512], gb[512];
    __shared__ int sa[512], sb[512];
    __shared__ unsigned int sedge[CHUNK];
    __shared__ unsigned short posb[CHUNK];
    int tid = threadIdx.x;
    int base = blockIdx.x * CHUNK;
    int n = min(CHUNK, E - base);
    for (int i = tid; i < 512; i += 256) hist[i] = 0;
    __syncthreads();
    for (int i = tid; i < n; i += 256) atomicAdd(&hist[dst[base + i] >> BSH], 1);
    __syncthreads();
    #pragma unroll
    for (int k = 0; k < 2; ++k) { int i = tid + k * 256; sa[i] = hist[i]; }
    __syncthreads();
    int* c = sa; int* nx = sb;
    for (int off = 1; off < 512; off <<= 1) {
        #pragma unroll
        for (int k = 0; k < 2; ++k) { int i = tid + k * 256; nx[i] = c[i] + (i >= off ? c[i - off] : 0); }
        __syncthreads();
        int* t = c; c = nx; nx = t;
    }
    #pragma unroll
    for (int k = 0; k < 2; ++k) {
        int i = tid + k * 256;
        int ex = c[i] - hist[i];
        lbase[i] = ex; cur2[i] = ex;
        if (i < B) gb[i] = hist[i] ? atomicAdd(&gcur[i], hist[i]) : 0;
    }
    for (int t = tid; t < B; t += 256) {
        int e0 = lbase[t], e1 = e0 + hist[t];
        for (int j = e0; j < e1; ++j) posb[j] = (unsigned short)t;
    }
    __syncthreads();
    for (int i = tid; i < n; i += 256) {
        int d = dst[base + i];
        int s = src[base + i];
        int b = d >> BSH;
        int p = atomicAdd(&cur2[b], 1);
        sedge[p] = ((unsigned int)s << BSH) | (unsigned int)(d & ((1 << BSH) - 1));
    }
    __syncthreads();
    for (int i = tid; i < n; i += 256) {
        int b = posb[i];
        bedge[gb[b] + (i - lbase[b])] = sedge[i];
    }
}

// ---------------- pass D: per-bucket CSR + degrees + dinv, all coalesced ----------------
__global__ __launch_bounds__(256) void bcsr_k(const unsigned int* __restrict__ bedge,
                                              const int* __restrict__ gbase,
                                              int* __restrict__ row_ptr, int* __restrict__ cnt,
                                              float* __restrict__ dinv, int* __restrict__ col,
                                              int N, int B) {
    __shared__ int hist[256], lofs[256], cur2[256];
    __shared__ int sa[256], sb[256];
    __shared__ int cols[CAP];
    int b = blockIdx.x, tid = threadIdx.x;
    int node0 = b << BSH;
    int g0 = gbase[b], g1 = gbase[b + 1];
    int n = g1 - g0;
    hist[tid] = 0;
    __syncthreads();
    for (int i = tid; i < n; i += 256) atomicAdd(&hist[bedge[g0 + i] & 255], 1);
    __syncthreads();
    sa[tid] = hist[tid];
    __syncthreads();
    int* c = sa; int* nx = sb;
    for (int off = 1; off < 256; off <<= 1) {
        nx[tid] = c[tid] + (tid >= off ? c[tid - off] : 0);
        __syncthreads();
        int* t = c; c = nx; nx = t;
    }
    int ex = c[tid] - hist[tid];
    lofs[tid] = ex; cur2[tid] = ex;
    int node = node0 + tid;
    if (node < N) {
        int deg = hist[tid];
        cnt[node] = deg;
        row_ptr[node] = g0 + ex;
        dinv[node] = rsqrtf((float)(deg + 1));
    }
    __syncthreads();
    for (int i = tid; i < n; i += 256) {
        unsigned int e = bedge[g0 + i];
        int p = atomicAdd(&cur2[e & 255], 1);
        if (p < CAP) cols[p] = (int)(e >> BSH);
    }
    __syncthreads();
    for (int i = tid; i < n; i += 256) col[g0 + i] = (i < CAP) ? cols[i] : 0;
}

// ---------------- graph boundaries from sorted batch ----------------
__global__ __launch_bounds__(256) void gbound_k(const int* __restrict__ batch, int* __restrict__ gstart,
                                                int N, int G) {
    int i = blockIdx.x * 256 + threadIdx.x;
    if (i >= N) return;
    int b = batch[i];
    int prev = (i == 0) ? -1 : batch[i - 1];
    for (int g = prev + 1; g <= b; ++g) gstart[g] = i;
    if (i == N - 1) {
        for (int g = b + 1; g <= G; ++g) gstart[g] = N;
    }
}

// ---------------- GEMM1: hs_bf = bf16( dinv[r] * (x @ W1) ),  [N,128]@[128,64] ----------------
__global__ __launch_bounds__(256) void gemm1_k(const float* __restrict__ x, const float* __restrict__ W1,
                                               const float* __restrict__ dinv, us* __restrict__ hsb, int N) {
    __shared__ float xT[128][64];   // k-major x tile
    __shared__ float wS[128][64];
    const int tid = threadIdx.x;
    const int row0 = blockIdx.x * 64;

    {   // W1: 8192 floats = 2048 f4, contiguous
        const f4* wsrc = (const f4*)W1;
        f4* wdst = (f4*)&wS[0][0];
        #pragma unroll
        for (int i = 0; i < 8; ++i) wdst[tid + i * 256] = wsrc[tid + i * 256];
    }
    {   // x tile rows row0..row0+63, transposed into LDS
        #pragma unroll
        for (int it = 0; it < 8; ++it) {
            int i = tid + it * 256;      // 0..2047
            int r = i & 63;
            int k4 = (i >> 6) * 4;       // 0..124
            int row = row0 + r;
            f4 v = (f4)(0.0f);
            if (row < N) v = *(const f4*)(x + (size_t)row * 128 + k4);
            xT[k4 + 0][r] = v.x; xT[k4 + 1][r] = v.y;
            xT[k4 + 2][r] = v.z; xT[k4 + 3][r] = v.w;
        }
    }
    __syncthreads();

    const int rl = (tid & 15) * 4;    // local rows rl..rl+3
    const int c0 = (tid >> 4) * 4;    // cols c0..c0+3
    f4 acc0 = (f4)(0.0f), acc1 = (f4)(0.0f), acc2 = (f4)(0.0f), acc3 = (f4)(0.0f);
    #pragma unroll 8
    for (int k = 0; k < 128; ++k) {
        f4 xa = *(const f4*)&xT[k][rl];
        f4 wb = *(const f4*)&wS[k][c0];
        acc0 += xa.x * wb;
        acc1 += xa.y * wb;
        acc2 += xa.z * wb;
        acc3 += xa.w * wb;
    }
    #pragma unroll
    for (int i = 0; i < 4; ++i) {
        int row = row0 + rl + i;
        if (row < N) {
            float di = dinv[row];
            f4 a = (i == 0) ? acc0 : (i == 1) ? acc1 : (i == 2) ? acc2 : acc3;
            a *= di;
            uint2 p;
            p.x = f2bf(a.x) | (f2bf(a.y) << 16);
            p.y = f2bf(a.z) | (f2bf(a.w) << 16);
            *(uint2*)(hsb + (size_t)row * 64 + c0) = p;
        }
    }
}

// ---------------- AGG1+GEMM2 fused: h2s_bf[i][c] = bf16( dinv[i] * (tanh_row @ W2)[c] ) ----------------
// wave per node: lane = channel of h1 row; W2 column slice preloaded in 16 VGPRs.
__global__ __launch_bounds__(256) void agg1_k(const us* __restrict__ hsb, const int* __restrict__ row_ptr,
                                              const int* __restrict__ cnt, const int* __restrict__ col,
                                              const float* __restrict__ dinv, const float* __restrict__ b1,
                                              const float* __restrict__ W2, us* __restrict__ h2sb, int N) {
    int wid = blockIdx.x * 4 + (threadIdx.x >> 6);
    int lane = threadIdx.x & 63;
    if (wid >= N) return;
    const int c16 = lane & 15;      // output channel (for the fused dot)
    const int hh  = lane >> 4;      // k-quarter 0..3
    float wreg[16];
    #pragma unroll
    for (int k = 0; k < 16; ++k) wreg[k] = W2[(hh * 16 + k) * 16 + c16];
    float bias = b1[lane];

    int beg = row_ptr[wid];
    int num = cnt[wid];
    float acc = 0.0f;
    for (int e0 = 0; e0 < num; e0 += 64) {
        int rem = num - e0;
        int el = 0;
        if (lane < rem) el = col[beg + e0 + lane];
        int m = rem < 64 ? rem : 64;
        int e = 0;
        for (; e + 4 <= m; e += 4) {
            int s0 = __shfl(el, e + 0), s1 = __shfl(el, e + 1);
            int s2 = __shfl(el, e + 2), s3 = __shfl(el, e + 3);
            float v0 = bf2f(hsb[(size_t)s0 * 64 + lane]);
            float v1 = bf2f(hsb[(size_t)s1 * 64 + lane]);
            float v2 = bf2f(hsb[(size_t)s2 * 64 + lane]);
            float v3 = bf2f(hsb[(size_t)s3 * 64 + lane]);
            acc += (v0 + v1) + (v2 + v3);
        }
        for (; e < m; ++e) {
            int s = __shfl(el, e);
            acc += bf2f(hsb[(size_t)s * 64 + lane]);
        }
    }
    float di = dinv[wid];
    float self = bf2f(hsb[(size_t)wid * 64 + lane]);
    float h1v = tanhf(di * (acc + self) + bias);

    // fused h1_row @ W2: lane (hh,c16) does k = hh*16..hh*16+15, then butterfly-add quarters
    float p = 0.0f;
    #pragma unroll
    for (int k = 0; k < 16; ++k) {
        float hv = __shfl(h1v, hh * 16 + k);
        p += hv * wreg[k];
    }
    p += __shfl_xor(p, 16);
    p += __shfl_xor(p, 32);
    if (lane < 16) h2sb[(size_t)wid * 16 + lane] = (us)f2bf(di * p);
}

// ---------------- AGG2: 16 channels, quarter-wave per node (bf16 table) ----------------
__global__ __launch_bounds__(256) void agg2_k(const us* __restrict__ h2sb, const int* __restrict__ row_ptr,
                                              const int* __restrict__ cnt, const int* __restrict__ col,
                                              const float* __restrict__ dinv, const float* __restrict__ b2,
                                              us* __restrict__ h2b, int N) {
    int t = blockIdx.x * 256 + threadIdx.x;
    int node = t >> 4;
    int c = t & 15;
    int sub = (threadIdx.x >> 4) & 3;   // quarter within wave
    if (node >= N) return;
    int beg = row_ptr[node];
    int num = cnt[node];
    float acc = 0.0f;
    for (int e0 = 0; e0 < num; e0 += 16) {
        int rem = num - e0;
        int el = 0;
        if (c < rem) el = col[beg + e0 + c];
        int m = rem < 16 ? rem : 16;
        for (int e = 0; e < m; ++e) {
            int s = __shfl(el, (sub << 4) + e);
            acc += bf2f(h2sb[(size_t)s * 16 + c]);
        }
    }
    float di = dinv[node];
    float self = bf2f(h2sb[(size_t)node * 16 + c]);
    h2b[(size_t)node * 16 + c] = (us)f2bf(tanhf(di * (acc + self) + b2[c]));
}

// ---------------- segmented pool + sigmoid: one block per graph ----------------
__global__ __launch_bounds__(256) void pool_seg_k(const us* __restrict__ h2b, const int* __restrict__ gstart,
                                                  float* __restrict__ out) {
    __shared__ float sd[16][16];   // [node-lane][channel]
    int g = blockIdx.x;
    int beg = gstart[g], end = gstart[g + 1];
    int tid = threadIdx.x;
    int c = tid & 15, r = tid >> 4;
    float acc = 0.0f;
    for (int i = beg + r; i < end; i += 16)
        acc += bf2f(h2b[(size_t)i * 16 + c]);
    sd[r][c] = acc;
    __syncthreads();
    if (r < 8) sd[r][c] += sd[r + 8][c];
    __syncthreads();
    if (r < 4) sd[r][c] += sd[r + 4][c];
    __syncthreads();
    if (r < 2) sd[r][c] += sd[r + 2][c];
    __syncthreads();
    if (r == 0) {
        float m = (sd[0][c] + sd[1][c]) / fmaxf((float)(end - beg), 1.0f);
        out[g * 16 + c] = 1.0f / (1.0f + expf(-m));
    }
}

extern "C" void kernel_launch(void* const* d_in, const int* in_sizes, int n_in,
                              void* d_out, int out_size, void* d_ws, size_t ws_size,
                              hipStream_t stream) {
    const float* x     = (const float*)d_in[0];
    const int*   ei    = (const int*)d_in[1];
    const int*   batch = (const int*)d_in[2];
    const float* W1    = (const float*)d_in[3];
    const float* b1    = (const float*)d_in[4];
    const float* W2    = (const float*)d_in[5];
    const float* b2    = (const float*)d_in[6];
    float* out = (float*)d_out;

    const int N = in_sizes[2];
    const int E = in_sizes[1] / 2;
    const int G = out_size / 16;
    const int* src = ei;
    const int* dst = ei + E;

    const int B = (N + 255) >> 8;              // 391 buckets (must be <= 512)
    const int nchunk = (E + CHUNK - 1) / CHUNK;

    char* w = (char*)d_ws;
    int*   bcnt     = (int*)w;    w += 512 * 4;
    int*   gbase    = (int*)w;    w += 520 * 4;
    int*   gcur     = (int*)w;    w += 512 * 4;
    int*   row_ptr  = (int*)w;    w += (size_t)N * 4;
    int*   cnt      = (int*)w;    w += (size_t)N * 4;
    float* dinv     = (float*)w;  w += (size_t)N * 4;
    int*   gstart   = (int*)w;    w += (size_t)(G + 1) * 4;
    int*   col      = (int*)w;    w += (size_t)E * 4;
    us*    hsb      = (us*)w;     w += (size_t)N * 64 * 2;
    us*    h2sb     = (us*)w;     w += (size_t)N * 16 * 2;
    us*    h2b      = (us*)w;     w += (size_t)N * 16 * 2;
    unsigned int* bedge = (unsigned int*)w;  w += (size_t)E * 4;

    hipMemsetAsync(bcnt, 0, 512 * 4, stream);

    bcount_k<<<nchunk, 256, 0, stream>>>(dst, bcnt, E, B);
    bscan_k <<<1, 256, 0, stream>>>(bcnt, gbase, gcur, B, E);
    bscat_k <<<nchunk, 256, 0, stream>>>(src, dst, gcur, bedge, E, B);
    bcsr_k  <<<B, 256, 0, stream>>>(bedge, gbase, row_ptr, cnt, dinv, col, N, B);
    gbound_k<<<(N + 255) / 256, 256, 0, stream>>>(batch, gstart, N, G);

    gemm1_k <<<(N + 63) / 64, 256, 0, stream>>>(x, W1, dinv, hsb, N);
    agg1_k  <<<(N + 3) / 4, 256, 0, stream>>>(hsb, row_ptr, cnt, col, dinv, b1, W2, h2sb, N);
    agg2_k  <<<((size_t)N * 16 + 255) / 256, 256, 0, stream>>>(h2sb, row_ptr, cnt, col, dinv, b2, h2b, N);
    pool_seg_k<<<G, 256, 0, stream>>>(h2b, gstart, out);
}